// Round 10
// baseline (508.100 us; speedup 1.0000x reference)
//
#include <hip/hip_runtime.h>
#include <hip/hip_bf16.h>
#include <stdint.h>

#define N_NODES 100000
#define N_EDGES 1600000
#define N_GRAPHS 512
#define IN_F 50
#define HID 128

#define NPART 8
#define PART_NODES ((N_NODES + NPART - 1) / NPART)   // 12500
#define BCAP 250000                                   // per-bucket capacity (E/8=200k, +40 sigma)

typedef __attribute__((ext_vector_type(8))) short bf16x8;
typedef __attribute__((ext_vector_type(4))) float f32x4;

__device__ __forceinline__ float bf2f(unsigned short s) {
    return __uint_as_float(((unsigned)s) << 16);
}
__device__ __forceinline__ unsigned short f2bf(float f) {
    unsigned u = __float_as_uint(f);
    u = (u + 0x7FFFu + ((u >> 16) & 1u)) >> 16;   // round-to-nearest-even
    return (unsigned short)u;
}

// ---------------- fused prep: xconv | zero deg+bucket_cnt | wconv | graph_ranges ----------------
#define PREP_W2 (N_NODES * 64)                  // xconv domain (6.4M)
#define PREP_W0 (N_NODES + NPART)               // deg zero + bucket_cnt zero
#define PREP_W1 (128 * 64 + 128 * 128)          // wconv domain
#define PREP_W3 (N_GRAPHS + 1)                  // graph_ranges
#define PREP_TOTAL (PREP_W2 + PREP_W0 + PREP_W1 + PREP_W3)

__global__ __launch_bounds__(256) void prep_all(
    const float* __restrict__ x, unsigned short* __restrict__ xbf,
    int* __restrict__ deg, int* __restrict__ bucket_cnt,
    const float* __restrict__ Wr1, const float* __restrict__ Wo1,
    const float* __restrict__ Wr2, const float* __restrict__ Wo2,
    const float* __restrict__ Wr3, const float* __restrict__ Wo3,
    unsigned short* __restrict__ o_r1, unsigned short* __restrict__ o_o1,
    unsigned short* __restrict__ o_r2, unsigned short* __restrict__ o_o2,
    unsigned short* __restrict__ o_r3, unsigned short* __restrict__ o_o3,
    const int* __restrict__ batch, int* __restrict__ gstart) {
    int idx = blockIdx.x * 256 + threadIdx.x;
    if (idx < PREP_W2) {                         // xconv: x[100k][50] f32 -> xbf[100k][64] bf16
        int n = idx >> 6, c = idx & 63;
        float v = (c < IN_F) ? x[(size_t)n * IN_F + c] : 0.f;
        xbf[idx] = f2bf(v);
        return;
    }
    idx -= PREP_W2;
    if (idx < PREP_W0) {                         // zero degree array + bucket counters
        if (idx < N_NODES) deg[idx] = 0;
        else bucket_cnt[idx - N_NODES] = 0;
        return;
    }
    idx -= PREP_W0;
    if (idx < PREP_W1) {                         // weight f32 -> bf16 (layer1 padded 50->64)
        if (idx < 128 * 64) {
            int n = idx >> 6, k = idx & 63;
            unsigned short a = 0, b = 0;
            if (k < IN_F) { a = f2bf(Wr1[n * IN_F + k]); b = f2bf(Wo1[n * IN_F + k]); }
            o_r1[idx] = a; o_o1[idx] = b;
        } else {
            int i2 = idx - 128 * 64;
            o_r2[i2] = f2bf(Wr2[i2]); o_o2[i2] = f2bf(Wo2[i2]);
            o_r3[i2] = f2bf(Wr3[i2]); o_o3[i2] = f2bf(Wo3[i2]);
        }
        return;
    }
    idx -= PREP_W1;
    if (idx < PREP_W3) {                         // graph_ranges (batch sorted)
        if (idx == N_GRAPHS) { gstart[idx] = N_NODES; return; }
        int lo = 0, hi = N_NODES;
        while (lo < hi) { int m = (lo + hi) >> 1; if (batch[m] < idx) lo = m + 1; else hi = m; }
        gstart[idx] = lo;
    }
}

// ---------------- two-level CSR build ----------------
// Phase A: bucket edges by dst partition. One pass over src+dst (coalesced), chunked
// coalesced pair writes (~2.5KB/bucket/block). Kills the 8x dst re-read + masked
// scattered src/csr writes of the one-level scheme (deg_hist ~50us + csr_fill 69us).
#define B1_BLOCKS 1024
#define B1_EPT ((N_EDGES + B1_BLOCKS * 256 - 1) / (B1_BLOCKS * 256))   // 7

__global__ __launch_bounds__(256) void bucket_scatter(const int* __restrict__ src,
                                                      const int* __restrict__ dst,
                                                      int* __restrict__ bucket_cnt,
                                                      uint2* __restrict__ pairs) {
    __shared__ int cnt[NPART], base[NPART];
    int t = threadIdx.x;
    if (t < NPART) cnt[t] = 0;
    __syncthreads();
    const int blockStart = blockIdx.x * (256 * B1_EPT);
    int dd[B1_EPT], kk[B1_EPT];
#pragma unroll
    for (int i = 0; i < B1_EPT; i++) {
        int e = blockStart + i * 256 + t;
        int d = (e < N_EDGES) ? dst[e] : -1;
        dd[i] = d;
        kk[i] = (d >= 0) ? (d / PART_NODES) : -1;
        if (kk[i] >= 0) atomicAdd(&cnt[kk[i]], 1);
    }
    __syncthreads();
    if (t < NPART) { base[t] = atomicAdd(&bucket_cnt[t], cnt[t]); cnt[t] = 0; }
    __syncthreads();
#pragma unroll
    for (int i = 0; i < B1_EPT; i++) {
        int k = kk[i];
        if (k >= 0) {
            int e = blockStart + i * 256 + t;
            int p = base[k] + atomicAdd(&cnt[k], 1);
            uint2 pr; pr.x = (unsigned)src[e]; pr.y = (unsigned)dd[i];
            pairs[(size_t)k * BCAP + p] = pr;
        }
    }
}

// Phase B: partition-local degree histogram. blockIdx&7 -> partition (round-robin
// block->XCD): bucket (1.6MB) + deg lines stay in that XCD's L2.
__global__ __launch_bounds__(256) void deg_hist(const int* __restrict__ bucket_cnt,
                                                const uint2* __restrict__ pairs,
                                                int* __restrict__ deg) {
    int part = blockIdx.x & (NPART - 1);
    int cnt = bucket_cnt[part];
    const uint2* bp = pairs + (size_t)part * BCAP;
    int base = (blockIdx.x >> 3) * 256 + threadIdx.x;
    int stride = (gridDim.x >> 3) * 256;
    for (int i = base; i < cnt; i += stride) atomicAdd(&deg[bp[i].y], 1);
}

// Phase D: partition-local fill (cursor + csr_src segment local to the XCD)
__global__ __launch_bounds__(256) void csr_fill(const int* __restrict__ bucket_cnt,
                                                const uint2* __restrict__ pairs,
                                                int* __restrict__ cursor,
                                                int* __restrict__ csr_src) {
    int part = blockIdx.x & (NPART - 1);
    int cnt = bucket_cnt[part];
    const uint2* bp = pairs + (size_t)part * BCAP;
    int base = (blockIdx.x >> 3) * 256 + threadIdx.x;
    int stride = (gridDim.x >> 3) * 256;
    for (int i = base; i < cnt; i += stride) {
        uint2 pr = bp[i];
        int p = atomicAdd(&cursor[pr.y], 1);
        csr_src[p] = (int)pr.x;
    }
}

// -------- 3-phase grid-wide exclusive scan of deg[100000] --------
#define SCAN_BLOCKS ((N_NODES + 1023) / 1024)   // 98

__global__ __launch_bounds__(256) void scan_phase1(const int* __restrict__ deg,
                                                   int* __restrict__ blocksum) {
    __shared__ int red[256];
    int b = blockIdx.x, t = threadIdx.x;
    int base = b * 1024 + t * 4;
    int s = 0;
#pragma unroll
    for (int i = 0; i < 4; i++) { int idx = base + i; if (idx < N_NODES) s += deg[idx]; }
    red[t] = s;
    __syncthreads();
    for (int off = 128; off > 0; off >>= 1) {
        if (t < off) red[t] += red[t + off];
        __syncthreads();
    }
    if (t == 0) blocksum[b] = red[0];
}

__global__ __launch_bounds__(128) void scan_phase2(const int* __restrict__ blocksum,
                                                   int* __restrict__ blockoff) {
    __shared__ int v[SCAN_BLOCKS];
    int t = threadIdx.x;
    if (t < SCAN_BLOCKS) v[t] = blocksum[t];
    __syncthreads();
    if (t == 0) {
        int run = 0;
        for (int i = 0; i < SCAN_BLOCKS; i++) { blockoff[i] = run; run += v[i]; }
        blockoff[SCAN_BLOCKS] = run;
    }
}

__global__ __launch_bounds__(256) void scan_phase3(const int* __restrict__ deg,
                                                   const int* __restrict__ blockoff,
                                                   int* __restrict__ rowptr,
                                                   int* __restrict__ cursor) {
    __shared__ int red[256];
    int b = blockIdx.x, t = threadIdx.x;
    int base = b * 1024 + t * 4;
    int e[4];
    int s = 0;
#pragma unroll
    for (int i = 0; i < 4; i++) {
        int idx = base + i;
        e[i] = (idx < N_NODES) ? deg[idx] : 0;
        s += e[i];
    }
    red[t] = s;
    __syncthreads();
    for (int off = 1; off < 256; off <<= 1) {
        int u = (t >= off) ? red[t - off] : 0;
        __syncthreads();
        red[t] += u;
        __syncthreads();
    }
    int prefix = red[t] - s + blockoff[b];
#pragma unroll
    for (int i = 0; i < 4; i++) {
        int idx = base + i;
        if (idx < N_NODES) { rowptr[idx] = prefix; cursor[idx] = prefix; prefix += e[i]; }
    }
    if (b == 0 && t == 0) rowptr[N_NODES] = blockoff[SCAN_BLOCKS];
}

// ---------------- pull aggregation ----------------
// layer 1: quarter-wave (16 lanes x uint2 = 128B row) per node, xbf [100k][64] bf16
__global__ __launch_bounds__(256) void gather_x64(const unsigned short* __restrict__ xbf,
                                                  const int* __restrict__ rowptr,
                                                  const int* __restrict__ csr_src,
                                                  unsigned short* __restrict__ aggbf) {
    int gid = blockIdx.x * 256 + threadIdx.x;
    int n = gid >> 4;
    int c = threadIdx.x & 15;
    if (n >= N_NODES) return;
    int jb = rowptr[n], je = rowptr[n + 1];
    const uint2* hu = reinterpret_cast<const uint2*>(xbf);
    float a0 = 0.f, a1 = 0.f, a2 = 0.f, a3 = 0.f;
    int j = jb;
    for (; j + 3 < je; j += 4) {
        int s0 = csr_src[j], s1 = csr_src[j + 1], s2 = csr_src[j + 2], s3 = csr_src[j + 3];
        uint2 v0 = hu[(size_t)s0 * 16 + c];
        uint2 v1 = hu[(size_t)s1 * 16 + c];
        uint2 v2 = hu[(size_t)s2 * 16 + c];
        uint2 v3 = hu[(size_t)s3 * 16 + c];
        a0 += (bf2f(v0.x & 0xFFFF) + bf2f(v1.x & 0xFFFF)) + (bf2f(v2.x & 0xFFFF) + bf2f(v3.x & 0xFFFF));
        a1 += (bf2f(v0.x >> 16) + bf2f(v1.x >> 16)) + (bf2f(v2.x >> 16) + bf2f(v3.x >> 16));
        a2 += (bf2f(v0.y & 0xFFFF) + bf2f(v1.y & 0xFFFF)) + (bf2f(v2.y & 0xFFFF) + bf2f(v3.y & 0xFFFF));
        a3 += (bf2f(v0.y >> 16) + bf2f(v1.y >> 16)) + (bf2f(v2.y >> 16) + bf2f(v3.y >> 16));
    }
    for (; j < je; j++) {
        int s0 = csr_src[j];
        uint2 v0 = hu[(size_t)s0 * 16 + c];
        a0 += bf2f(v0.x & 0xFFFF);
        a1 += bf2f(v0.x >> 16);
        a2 += bf2f(v0.y & 0xFFFF);
        a3 += bf2f(v0.y >> 16);
    }
    uint2 pk;
    pk.x = (unsigned)f2bf(a0) | ((unsigned)f2bf(a1) << 16);
    pk.y = (unsigned)f2bf(a2) | ((unsigned)f2bf(a3) << 16);
    reinterpret_cast<uint2*>(aggbf)[(size_t)n * 16 + c] = pk;
}

// layers 2/3: half-wave (32 lanes x uint2 = 256B row) per node, h [100k][128] bf16
__global__ __launch_bounds__(256) void gather_bf128(const unsigned short* __restrict__ h,
                                                    const int* __restrict__ rowptr,
                                                    const int* __restrict__ csr_src,
                                                    unsigned short* __restrict__ aggbf) {
    int gid = blockIdx.x * 256 + threadIdx.x;
    int n = gid >> 5;
    int c = threadIdx.x & 31;
    if (n >= N_NODES) return;
    int jb = rowptr[n], je = rowptr[n + 1];
    const uint2* hu = reinterpret_cast<const uint2*>(h);
    float a0 = 0.f, a1 = 0.f, a2 = 0.f, a3 = 0.f;
    int j = jb;
    for (; j + 3 < je; j += 4) {
        int s0 = csr_src[j], s1 = csr_src[j + 1], s2 = csr_src[j + 2], s3 = csr_src[j + 3];
        uint2 v0 = hu[(size_t)s0 * 32 + c];
        uint2 v1 = hu[(size_t)s1 * 32 + c];
        uint2 v2 = hu[(size_t)s2 * 32 + c];
        uint2 v3 = hu[(size_t)s3 * 32 + c];
        a0 += (bf2f(v0.x & 0xFFFF) + bf2f(v1.x & 0xFFFF)) + (bf2f(v2.x & 0xFFFF) + bf2f(v3.x & 0xFFFF));
        a1 += (bf2f(v0.x >> 16) + bf2f(v1.x >> 16)) + (bf2f(v2.x >> 16) + bf2f(v3.x >> 16));
        a2 += (bf2f(v0.y & 0xFFFF) + bf2f(v1.y & 0xFFFF)) + (bf2f(v2.y & 0xFFFF) + bf2f(v3.y & 0xFFFF));
        a3 += (bf2f(v0.y >> 16) + bf2f(v1.y >> 16)) + (bf2f(v2.y >> 16) + bf2f(v3.y >> 16));
    }
    for (; j < je; j++) {
        int s0 = csr_src[j];
        uint2 v0 = hu[(size_t)s0 * 32 + c];
        a0 += bf2f(v0.x & 0xFFFF);
        a1 += bf2f(v0.x >> 16);
        a2 += bf2f(v0.y & 0xFFFF);
        a3 += bf2f(v0.y >> 16);
    }
    uint2 pk;
    pk.x = (unsigned)f2bf(a0) | ((unsigned)f2bf(a1) << 16);
    pk.y = (unsigned)f2bf(a2) | ((unsigned)f2bf(a3) << 16);
    reinterpret_cast<uint2*>(aggbf)[(size_t)n * 32 + c] = pk;
}

// ---------------- MFMA fused linear (no atomics) ----------------
// out = [relu](A1 @ B1^T + bias + A2 @ B2^T), stored bf16. A bf16 [M][K], B bf16 [128][K].
// Block = 256 thr = 4 waves; BM=128 (wave owns 32 rows = 2 m-tiles). Weights in LDS,
// PITCH = K*2+16. Operands swapped in MFMA: D = W_frag x A_frag -> lane&15 = node,
// (lane>>4)*4+reg = 4 consecutive out cols -> uint2 contiguous stores.
// In-place safe (hout may alias A1 or A2).
template <int K1, int K2, bool RELU>
__global__ __launch_bounds__(256) void mfma_linear(
    const unsigned short* __restrict__ A1, const unsigned short* __restrict__ A2,
    const unsigned short* __restrict__ B1, const unsigned short* __restrict__ B2,
    const float* __restrict__ bias, unsigned short* __restrict__ hout) {
    constexpr int P1 = K1 * 2 + 16;
    constexpr int P2 = K2 * 2 + 16;
    constexpr int PMAX = (P1 > P2 ? P1 : P2);
    __shared__ __align__(16) unsigned char ldsb[128 * PMAX];

    const int tid = threadIdx.x;
    const int lane = tid & 63;
    const int wave = tid >> 6;
    const int ar = lane & 15;
    const int kh = lane >> 4;
    const int m0 = blockIdx.x * 128 + wave * 32;

    f32x4 acc0[8], acc1[8];
#pragma unroll
    for (int nt = 0; nt < 8; nt++) {
        acc0[nt] = (f32x4){0.f, 0.f, 0.f, 0.f};
        acc1[nt] = (f32x4){0.f, 0.f, 0.f, 0.f};
    }

    int r0 = m0 + ar;      if (r0 > N_NODES - 1) r0 = N_NODES - 1;
    int r1 = m0 + 16 + ar; if (r1 > N_NODES - 1) r1 = N_NODES - 1;

    // ---- stage B1 ----
    {
        constexpr int CPR = K1 / 8;
#pragma unroll
        for (int ci = 0; ci < 128 * CPR / 256; ci++) {
            int c = ci * 256 + tid;
            int n = c / CPR, slot = c - n * CPR;
            uint4 v = *reinterpret_cast<const uint4*>(B1 + n * K1 + slot * 8);
            *reinterpret_cast<uint4*>(&ldsb[n * P1 + slot * 16]) = v;
        }
    }
    __syncthreads();
    // ---- K-loop 1 ----
    {
        const unsigned short* a0p = A1 + (size_t)r0 * K1 + kh * 8;
        const unsigned short* a1p = A1 + (size_t)r1 * K1 + kh * 8;
#pragma unroll
        for (int ks = 0; ks < K1 / 32; ks++) {
            bf16x8 a0 = *reinterpret_cast<const bf16x8*>(a0p + ks * 32);
            bf16x8 a1 = *reinterpret_cast<const bf16x8*>(a1p + ks * 32);
#pragma unroll
            for (int nt = 0; nt < 8; nt++) {
                bf16x8 b = *reinterpret_cast<const bf16x8*>(
                    &ldsb[(nt * 16 + ar) * P1 + ks * 64 + kh * 16]);
                acc0[nt] = __builtin_amdgcn_mfma_f32_16x16x32_bf16(b, a0, acc0[nt], 0, 0, 0);
                acc1[nt] = __builtin_amdgcn_mfma_f32_16x16x32_bf16(b, a1, acc1[nt], 0, 0, 0);
            }
        }
    }
    __syncthreads();
    // ---- stage B2 ----
    {
        constexpr int CPR = K2 / 8;
#pragma unroll
        for (int ci = 0; ci < 128 * CPR / 256; ci++) {
            int c = ci * 256 + tid;
            int n = c / CPR, slot = c - n * CPR;
            uint4 v = *reinterpret_cast<const uint4*>(B2 + n * K2 + slot * 8);
            *reinterpret_cast<uint4*>(&ldsb[n * P2 + slot * 16]) = v;
        }
    }
    __syncthreads();
    // ---- K-loop 2 ----
    {
        const unsigned short* a0p = A2 + (size_t)r0 * K2 + kh * 8;
        const unsigned short* a1p = A2 + (size_t)r1 * K2 + kh * 8;
#pragma unroll
        for (int ks = 0; ks < K2 / 32; ks++) {
            bf16x8 a0 = *reinterpret_cast<const bf16x8*>(a0p + ks * 32);
            bf16x8 a1 = *reinterpret_cast<const bf16x8*>(a1p + ks * 32);
#pragma unroll
            for (int nt = 0; nt < 8; nt++) {
                bf16x8 b = *reinterpret_cast<const bf16x8*>(
                    &ldsb[(nt * 16 + ar) * P2 + ks * 64 + kh * 16]);
                acc0[nt] = __builtin_amdgcn_mfma_f32_16x16x32_bf16(b, a0, acc0[nt], 0, 0, 0);
                acc1[nt] = __builtin_amdgcn_mfma_f32_16x16x32_bf16(b, a1, acc1[nt], 0, 0, 0);
            }
        }
    }

    // ---- epilogue ----
    float4 bv[8];
#pragma unroll
    for (int nt = 0; nt < 8; nt++)
        bv[nt] = *reinterpret_cast<const float4*>(bias + nt * 16 + kh * 4);

    int node0 = m0 + ar;
    int node1 = m0 + 16 + ar;
    if (node0 < N_NODES) {
#pragma unroll
        for (int nt = 0; nt < 8; nt++) {
            float v0 = acc0[nt][0] + bv[nt].x;
            float v1 = acc0[nt][1] + bv[nt].y;
            float v2 = acc0[nt][2] + bv[nt].z;
            float v3 = acc0[nt][3] + bv[nt].w;
            if (RELU) { v0 = fmaxf(v0, 0.f); v1 = fmaxf(v1, 0.f); v2 = fmaxf(v2, 0.f); v3 = fmaxf(v3, 0.f); }
            uint2 pk;
            pk.x = (unsigned)f2bf(v0) | ((unsigned)f2bf(v1) << 16);
            pk.y = (unsigned)f2bf(v2) | ((unsigned)f2bf(v3) << 16);
            *reinterpret_cast<uint2*>(hout + (size_t)node0 * HID + nt * 16 + kh * 4) = pk;
        }
    }
    if (node1 < N_NODES) {
#pragma unroll
        for (int nt = 0; nt < 8; nt++) {
            float v0 = acc1[nt][0] + bv[nt].x;
            float v1 = acc1[nt][1] + bv[nt].y;
            float v2 = acc1[nt][2] + bv[nt].z;
            float v3 = acc1[nt][3] + bv[nt].w;
            if (RELU) { v0 = fmaxf(v0, 0.f); v1 = fmaxf(v1, 0.f); v2 = fmaxf(v2, 0.f); v3 = fmaxf(v3, 0.f); }
            uint2 pk;
            pk.x = (unsigned)f2bf(v0) | ((unsigned)f2bf(v1) << 16);
            pk.y = (unsigned)f2bf(v2) | ((unsigned)f2bf(v3) << 16);
            *reinterpret_cast<uint2*>(hout + (size_t)node1 * HID + nt * 16 + kh * 4) = pk;
        }
    }
}

// ---------------- fused mean-pool + final linear (atomic-free) ----------------
__global__ __launch_bounds__(256) void pool_final(const unsigned short* __restrict__ h3,
                                                  const int* __restrict__ gstart,
                                                  const float* __restrict__ W_lin,
                                                  const float* __restrict__ b_lin,
                                                  float* __restrict__ out) {
    __shared__ float pp[4][HID];
    int g = blockIdx.x, t = threadIdx.x;
    int wave = t >> 6, lane = t & 63;
    int s0 = gstart[g], s1 = gstart[g + 1];
    const unsigned* h3u = reinterpret_cast<const unsigned*>(h3);
    float a0 = 0.f, a1 = 0.f;
    for (int n = s0 + wave; n < s1; n += 4) {
        unsigned v = h3u[(size_t)n * 64 + lane];
        a0 += bf2f((unsigned short)(v & 0xFFFF));
        a1 += bf2f((unsigned short)(v >> 16));
    }
    pp[wave][2 * lane] = a0;
    pp[wave][2 * lane + 1] = a1;
    __syncthreads();
    if (wave == 0) {
        float c = fmaxf((float)(s1 - s0), 1.f);
        float r0 = ((pp[0][2 * lane] + pp[1][2 * lane]) + (pp[2][2 * lane] + pp[3][2 * lane])) / c;
        float r1 = ((pp[0][2 * lane + 1] + pp[1][2 * lane + 1]) + (pp[2][2 * lane + 1] + pp[3][2 * lane + 1])) / c;
        pp[0][2 * lane] = r0;
        pp[0][2 * lane + 1] = r1;
    }
    __syncthreads();
    if (t < 4) {
        float s = b_lin[t];
#pragma unroll 8
        for (int k = 0; k < HID; k++) s += pp[0][k] * W_lin[t * HID + k];
        out[g * 4 + t] = s;
    }
}

extern "C" void kernel_launch(void* const* d_in, const int* in_sizes, int n_in,
                              void* d_out, int out_size, void* d_ws, size_t ws_size,
                              hipStream_t stream) {
    (void)in_sizes; (void)n_in; (void)out_size; (void)ws_size;
    const float* x      = (const float*)d_in[0];
    const int*   ei     = (const int*)d_in[1];
    const int*   batch  = (const int*)d_in[2];
    const float* W_rel1 = (const float*)d_in[3];
    const float* b_rel1 = (const float*)d_in[4];
    const float* W_root1= (const float*)d_in[5];
    const float* W_rel2 = (const float*)d_in[6];
    const float* b_rel2 = (const float*)d_in[7];
    const float* W_root2= (const float*)d_in[8];
    const float* W_rel3 = (const float*)d_in[9];
    const float* b_rel3 = (const float*)d_in[10];
    const float* W_root3= (const float*)d_in[11];
    const float* W_lin  = (const float*)d_in[12];
    const float* b_lin  = (const float*)d_in[13];
    const int* src = ei;
    const int* dst = ei + N_EDGES;

    char* ws = (char*)d_ws;
    size_t off = 0;
    auto alloc = [&](size_t bytes) { void* p = ws + off; off += (bytes + 255) & ~(size_t)255; return p; };
    unsigned short* aggbf    = (unsigned short*)alloc((size_t)N_NODES * HID * 2); // layer1 [.][64] slice; layer3 h3 in-place
    unsigned short* h1       = (unsigned short*)alloc((size_t)N_NODES * HID * 2); // layer 2 in-place
    unsigned short* xbf      = (unsigned short*)alloc((size_t)N_NODES * 64 * 2);
    int*            deg      = (int*)alloc((size_t)N_NODES * 4);
    int*            rowptr   = (int*)alloc((size_t)(N_NODES + 1) * 4);
    int*            cursor   = (int*)alloc((size_t)N_NODES * 4);
    int*            csr_src  = (int*)alloc((size_t)N_EDGES * 4);
    uint2*          pairs    = (uint2*)alloc((size_t)NPART * BCAP * 8);          // 16 MB
    int*            bucket_cnt = (int*)alloc(NPART * 4);
    int*            blocksum = (int*)alloc((size_t)(SCAN_BLOCKS + 1) * 4);
    int*            blockoff = (int*)alloc((size_t)(SCAN_BLOCKS + 1) * 4);
    int*            gstart   = (int*)alloc((size_t)(N_GRAPHS + 1) * 4);
    unsigned short* Wb_rel1  = (unsigned short*)alloc(128 * 64 * 2);
    unsigned short* Wb_root1 = (unsigned short*)alloc(128 * 64 * 2);
    unsigned short* Wb_rel2  = (unsigned short*)alloc(128 * 128 * 2);
    unsigned short* Wb_root2 = (unsigned short*)alloc(128 * 128 * 2);
    unsigned short* Wb_rel3  = (unsigned short*)alloc(128 * 128 * 2);
    unsigned short* Wb_root3 = (unsigned short*)alloc(128 * 128 * 2);

    // ---- fused prep (xconv | zero deg+bucket_cnt | wconv | graph_ranges)
    prep_all<<<(PREP_TOTAL + 255) / 256, 256, 0, stream>>>(
        x, xbf, deg, bucket_cnt, W_rel1, W_root1, W_rel2, W_root2, W_rel3, W_root3,
        Wb_rel1, Wb_root1, Wb_rel2, Wb_root2, Wb_rel3, Wb_root3, batch, gstart);

    // ---- two-level CSR build
    bucket_scatter<<<B1_BLOCKS, 256, 0, stream>>>(src, dst, bucket_cnt, pairs);
    deg_hist<<<2048, 256, 0, stream>>>(bucket_cnt, pairs, deg);
    scan_phase1<<<SCAN_BLOCKS, 256, 0, stream>>>(deg, blocksum);
    scan_phase2<<<1, 128, 0, stream>>>(blocksum, blockoff);
    scan_phase3<<<SCAN_BLOCKS, 256, 0, stream>>>(deg, blockoff, rowptr, cursor);
    csr_fill<<<2048, 256, 0, stream>>>(bucket_cnt, pairs, cursor, csr_src);

    const int MFMA_BLOCKS = (N_NODES + 127) / 128;   // BM=128

    // ---- layer 1: pull-aggregate xbf (bf16, 128B rows), MFMA + relu -> h1
    gather_x64<<<(N_NODES * 16 + 255) / 256, 256, 0, stream>>>(xbf, rowptr, csr_src, aggbf);
    mfma_linear<64, 64, true><<<MFMA_BLOCKS, 256, 0, stream>>>(
        aggbf, xbf, Wb_rel1, Wb_root1, b_rel1, h1);

    // ---- layer 2: pull-aggregate h1, MFMA + relu -> h1 (in-place)
    gather_bf128<<<(N_NODES * 32 + 255) / 256, 256, 0, stream>>>(h1, rowptr, csr_src, aggbf);
    mfma_linear<128, 128, true><<<MFMA_BLOCKS, 256, 0, stream>>>(
        aggbf, h1, Wb_rel2, Wb_root2, b_rel2, h1);

    // ---- layer 3: pull-aggregate h1, MFMA (no relu) -> h3 (in-place over aggbf)
    gather_bf128<<<(N_NODES * 32 + 255) / 256, 256, 0, stream>>>(h1, rowptr, csr_src, aggbf);
    mfma_linear<128, 128, false><<<MFMA_BLOCKS, 256, 0, stream>>>(
        aggbf, h1, Wb_rel3, Wb_root3, b_rel3, aggbf);

    // ---- atomic-free mean-pool + final linear
    pool_final<<<N_GRAPHS, 256, 0, stream>>>(aggbf, gstart, W_lin, b_lin, (float*)d_out);
}

// Round 11
// 399.562 us; speedup vs baseline: 1.2716x; 1.2716x over previous
//
#include <hip/hip_runtime.h>
#include <hip/hip_bf16.h>
#include <stdint.h>

#define N_NODES 100000
#define N_EDGES 1600000
#define N_GRAPHS 512
#define IN_F 50
#define HID 128

#define NPART 64
#define PART_NODES ((N_NODES + NPART - 1) / NPART)   // 1563 (64*1563 = 100032)
#define BCAP 28000                                    // per-bucket capacity (mean 25000, +19 sigma)

typedef __attribute__((ext_vector_type(8))) short bf16x8;
typedef __attribute__((ext_vector_type(4))) float f32x4;

__device__ __forceinline__ float bf2f(unsigned short s) {
    return __uint_as_float(((unsigned)s) << 16);
}
__device__ __forceinline__ unsigned short f2bf(float f) {
    unsigned u = __float_as_uint(f);
    u = (u + 0x7FFFu + ((u >> 16) & 1u)) >> 16;   // round-to-nearest-even
    return (unsigned short)u;
}

// ---------------- fused prep: xconv | zero bucket_cnt + rowptr tail | wconv | graph_ranges ----------------
#define PREP_W2 (N_NODES * 64)                  // xconv domain (6.4M)
#define PREP_W0 (NPART + 1)                     // bucket_cnt zero + rowptr[N_NODES]
#define PREP_W1 (128 * 64 + 128 * 128)          // wconv domain
#define PREP_W3 (N_GRAPHS + 1)                  // graph_ranges
#define PREP_TOTAL (PREP_W2 + PREP_W0 + PREP_W1 + PREP_W3)

__global__ __launch_bounds__(256) void prep_all(
    const float* __restrict__ x, unsigned short* __restrict__ xbf,
    int* __restrict__ bucket_cnt, int* __restrict__ rowptr,
    const float* __restrict__ Wr1, const float* __restrict__ Wo1,
    const float* __restrict__ Wr2, const float* __restrict__ Wo2,
    const float* __restrict__ Wr3, const float* __restrict__ Wo3,
    unsigned short* __restrict__ o_r1, unsigned short* __restrict__ o_o1,
    unsigned short* __restrict__ o_r2, unsigned short* __restrict__ o_o2,
    unsigned short* __restrict__ o_r3, unsigned short* __restrict__ o_o3,
    const int* __restrict__ batch, int* __restrict__ gstart) {
    int idx = blockIdx.x * 256 + threadIdx.x;
    if (idx < PREP_W2) {                         // xconv: x[100k][50] f32 -> xbf[100k][64] bf16
        int n = idx >> 6, c = idx & 63;
        float v = (c < IN_F) ? x[(size_t)n * IN_F + c] : 0.f;
        xbf[idx] = f2bf(v);
        return;
    }
    idx -= PREP_W2;
    if (idx < PREP_W0) {
        if (idx < NPART) bucket_cnt[idx] = 0;
        else rowptr[N_NODES] = N_EDGES;          // constant tail
        return;
    }
    idx -= PREP_W0;
    if (idx < PREP_W1) {                         // weight f32 -> bf16 (layer1 padded 50->64)
        if (idx < 128 * 64) {
            int n = idx >> 6, k = idx & 63;
            unsigned short a = 0, b = 0;
            if (k < IN_F) { a = f2bf(Wr1[n * IN_F + k]); b = f2bf(Wo1[n * IN_F + k]); }
            o_r1[idx] = a; o_o1[idx] = b;
        } else {
            int i2 = idx - 128 * 64;
            o_r2[i2] = f2bf(Wr2[i2]); o_o2[i2] = f2bf(Wo2[i2]);
            o_r3[i2] = f2bf(Wr3[i2]); o_o3[i2] = f2bf(Wo3[i2]);
        }
        return;
    }
    idx -= PREP_W1;
    if (idx < PREP_W3) {                         // graph_ranges (batch sorted)
        if (idx == N_GRAPHS) { gstart[idx] = N_NODES; return; }
        int lo = 0, hi = N_NODES;
        while (lo < hi) { int m = (lo + hi) >> 1; if (batch[m] < idx) lo = m + 1; else hi = m; }
        gstart[idx] = lo;
    }
}

// ---------------- CSR build, LDS-cursor two-level ----------------
// Phase A: bucket edges by dst partition (64 buckets). One coalesced pass over src+dst;
// pairs packed into ONE uint: (src<<11) | local_dst  (src<2^17, local<1563<2^11).
#define B1_BLOCKS 256
#define B1_EPT ((N_EDGES + B1_BLOCKS * 256 - 1) / (B1_BLOCKS * 256))   // 25

__global__ __launch_bounds__(256) void bucket_scatter(const int* __restrict__ src,
                                                      const int* __restrict__ dst,
                                                      int* __restrict__ bucket_cnt,
                                                      unsigned* __restrict__ pairs) {
    __shared__ int cnt[NPART], base[NPART];
    int t = threadIdx.x;
    for (int i = t; i < NPART; i += 256) cnt[i] = 0;
    __syncthreads();
    const int blockStart = blockIdx.x * (256 * B1_EPT);
    int kk[B1_EPT];
    unsigned ww[B1_EPT];
#pragma unroll
    for (int i = 0; i < B1_EPT; i++) {
        int e = blockStart + i * 256 + t;
        if (e < N_EDGES) {
            int d = dst[e];
            int k = d / PART_NODES;
            int local = d - k * PART_NODES;
            kk[i] = k;
            ww[i] = ((unsigned)src[e] << 11) | (unsigned)local;
            atomicAdd(&cnt[k], 1);
        } else kk[i] = -1;
    }
    __syncthreads();
    for (int i = t; i < NPART; i += 256) { base[i] = atomicAdd(&bucket_cnt[i], cnt[i]); cnt[i] = 0; }
    __syncthreads();
#pragma unroll
    for (int i = 0; i < B1_EPT; i++) {
        int k = kk[i];
        if (k >= 0) {
            int p = base[k] + atomicAdd(&cnt[k], 1);
            pairs[(size_t)k * BCAP + p] = ww[i];
        }
    }
}

// Phase B: one block per partition. LDS histogram -> block scan -> rowptr segment ->
// LDS-cursor fill. ZERO global atomics (R10 lesson: 1.6M device-scope cursor atomics
// are fabric round-trips regardless of data locality; csr_fill+deg_hist were 123us).
#define LCSR_T 512
#define LCH ((PART_NODES + LCSR_T - 1) / LCSR_T)    // 4 (512*4 = 2048 >= 1563)

__global__ __launch_bounds__(LCSR_T) void local_csr(const int* __restrict__ bucket_cnt,
                                                    const unsigned* __restrict__ pairs,
                                                    int* __restrict__ rowptr,
                                                    int* __restrict__ csr_src) {
    __shared__ int cur[PART_NODES];    // counts -> exclusive offsets -> cursors
    __shared__ int red[LCSR_T];
    __shared__ int pb[NPART];
    const int p = blockIdx.x, t = threadIdx.x;
    const int cnt = bucket_cnt[p];
    const unsigned* bp = pairs + (size_t)p * BCAP;
    const int plo = p * PART_NODES;

    for (int i = t; i < PART_NODES; i += LCSR_T) cur[i] = 0;
    if (t < NPART) pb[t] = bucket_cnt[t];
    __syncthreads();
    // partition base = prefix of bucket counts (tiny serial in LDS by thread 0)
    if (t == 0) {
        int s = 0;
        for (int i = 0; i < NPART; i++) { int v = pb[i]; pb[i] = s; s += v; }
    }
    // pass 1: LDS histogram
    for (int i = t; i < cnt; i += LCSR_T) atomicAdd(&cur[bp[i] & 2047u], 1);
    __syncthreads();
    const int pbase = pb[p];
    // block-local exclusive scan over PART_NODES counts (thread owns LCH contiguous)
    int e[LCH];
    int s = 0;
#pragma unroll
    for (int i = 0; i < LCH; i++) {
        int idx = t * LCH + i;
        e[i] = (idx < PART_NODES) ? cur[idx] : 0;
        s += e[i];
    }
    red[t] = s;
    __syncthreads();
    for (int o = 1; o < LCSR_T; o <<= 1) {
        int u = (t >= o) ? red[t - o] : 0;
        __syncthreads();
        red[t] += u;
        __syncthreads();
    }
    int run = red[t] - s;   // exclusive prefix of this thread's chunk
#pragma unroll
    for (int i = 0; i < LCH; i++) {
        int idx = t * LCH + i;
        if (idx < PART_NODES) {
            cur[idx] = run;                      // cursor = exclusive offset
            int node = plo + idx;
            if (node < N_NODES) rowptr[node] = pbase + run;
            run += e[i];
        }
    }
    __syncthreads();
    // pass 2: fill via LDS cursors; csr_src segment [pbase, pbase+cnt) is contiguous
    for (int i = t; i < cnt; i += LCSR_T) {
        unsigned v = bp[i];
        int pos = pbase + atomicAdd(&cur[v & 2047u], 1);
        csr_src[pos] = (int)(v >> 11);
    }
}

// ---------------- pull aggregation ----------------
// layer 1: quarter-wave (16 lanes x uint2 = 128B row) per node, xbf [100k][64] bf16
__global__ __launch_bounds__(256) void gather_x64(const unsigned short* __restrict__ xbf,
                                                  const int* __restrict__ rowptr,
                                                  const int* __restrict__ csr_src,
                                                  unsigned short* __restrict__ aggbf) {
    int gid = blockIdx.x * 256 + threadIdx.x;
    int n = gid >> 4;
    int c = threadIdx.x & 15;
    if (n >= N_NODES) return;
    int jb = rowptr[n], je = rowptr[n + 1];
    const uint2* hu = reinterpret_cast<const uint2*>(xbf);
    float a0 = 0.f, a1 = 0.f, a2 = 0.f, a3 = 0.f;
    int j = jb;
    for (; j + 3 < je; j += 4) {
        int s0 = csr_src[j], s1 = csr_src[j + 1], s2 = csr_src[j + 2], s3 = csr_src[j + 3];
        uint2 v0 = hu[(size_t)s0 * 16 + c];
        uint2 v1 = hu[(size_t)s1 * 16 + c];
        uint2 v2 = hu[(size_t)s2 * 16 + c];
        uint2 v3 = hu[(size_t)s3 * 16 + c];
        a0 += (bf2f(v0.x & 0xFFFF) + bf2f(v1.x & 0xFFFF)) + (bf2f(v2.x & 0xFFFF) + bf2f(v3.x & 0xFFFF));
        a1 += (bf2f(v0.x >> 16) + bf2f(v1.x >> 16)) + (bf2f(v2.x >> 16) + bf2f(v3.x >> 16));
        a2 += (bf2f(v0.y & 0xFFFF) + bf2f(v1.y & 0xFFFF)) + (bf2f(v2.y & 0xFFFF) + bf2f(v3.y & 0xFFFF));
        a3 += (bf2f(v0.y >> 16) + bf2f(v1.y >> 16)) + (bf2f(v2.y >> 16) + bf2f(v3.y >> 16));
    }
    for (; j < je; j++) {
        int s0 = csr_src[j];
        uint2 v0 = hu[(size_t)s0 * 16 + c];
        a0 += bf2f(v0.x & 0xFFFF);
        a1 += bf2f(v0.x >> 16);
        a2 += bf2f(v0.y & 0xFFFF);
        a3 += bf2f(v0.y >> 16);
    }
    uint2 pk;
    pk.x = (unsigned)f2bf(a0) | ((unsigned)f2bf(a1) << 16);
    pk.y = (unsigned)f2bf(a2) | ((unsigned)f2bf(a3) << 16);
    reinterpret_cast<uint2*>(aggbf)[(size_t)n * 16 + c] = pk;
}

// layers 2/3: half-wave (32 lanes x uint2 = 256B row) per node, h [100k][128] bf16
__global__ __launch_bounds__(256) void gather_bf128(const unsigned short* __restrict__ h,
                                                    const int* __restrict__ rowptr,
                                                    const int* __restrict__ csr_src,
                                                    unsigned short* __restrict__ aggbf) {
    int gid = blockIdx.x * 256 + threadIdx.x;
    int n = gid >> 5;
    int c = threadIdx.x & 31;
    if (n >= N_NODES) return;
    int jb = rowptr[n], je = rowptr[n + 1];
    const uint2* hu = reinterpret_cast<const uint2*>(h);
    float a0 = 0.f, a1 = 0.f, a2 = 0.f, a3 = 0.f;
    int j = jb;
    for (; j + 3 < je; j += 4) {
        int s0 = csr_src[j], s1 = csr_src[j + 1], s2 = csr_src[j + 2], s3 = csr_src[j + 3];
        uint2 v0 = hu[(size_t)s0 * 32 + c];
        uint2 v1 = hu[(size_t)s1 * 32 + c];
        uint2 v2 = hu[(size_t)s2 * 32 + c];
        uint2 v3 = hu[(size_t)s3 * 32 + c];
        a0 += (bf2f(v0.x & 0xFFFF) + bf2f(v1.x & 0xFFFF)) + (bf2f(v2.x & 0xFFFF) + bf2f(v3.x & 0xFFFF));
        a1 += (bf2f(v0.x >> 16) + bf2f(v1.x >> 16)) + (bf2f(v2.x >> 16) + bf2f(v3.x >> 16));
        a2 += (bf2f(v0.y & 0xFFFF) + bf2f(v1.y & 0xFFFF)) + (bf2f(v2.y & 0xFFFF) + bf2f(v3.y & 0xFFFF));
        a3 += (bf2f(v0.y >> 16) + bf2f(v1.y >> 16)) + (bf2f(v2.y >> 16) + bf2f(v3.y >> 16));
    }
    for (; j < je; j++) {
        int s0 = csr_src[j];
        uint2 v0 = hu[(size_t)s0 * 32 + c];
        a0 += bf2f(v0.x & 0xFFFF);
        a1 += bf2f(v0.x >> 16);
        a2 += bf2f(v0.y & 0xFFFF);
        a3 += bf2f(v0.y >> 16);
    }
    uint2 pk;
    pk.x = (unsigned)f2bf(a0) | ((unsigned)f2bf(a1) << 16);
    pk.y = (unsigned)f2bf(a2) | ((unsigned)f2bf(a3) << 16);
    reinterpret_cast<uint2*>(aggbf)[(size_t)n * 32 + c] = pk;
}

// ---------------- MFMA fused linear (no atomics) ----------------
template <int K1, int K2, bool RELU>
__global__ __launch_bounds__(256) void mfma_linear(
    const unsigned short* __restrict__ A1, const unsigned short* __restrict__ A2,
    const unsigned short* __restrict__ B1, const unsigned short* __restrict__ B2,
    const float* __restrict__ bias, unsigned short* __restrict__ hout) {
    constexpr int P1 = K1 * 2 + 16;
    constexpr int P2 = K2 * 2 + 16;
    constexpr int PMAX = (P1 > P2 ? P1 : P2);
    __shared__ __align__(16) unsigned char ldsb[128 * PMAX];

    const int tid = threadIdx.x;
    const int lane = tid & 63;
    const int wave = tid >> 6;
    const int ar = lane & 15;
    const int kh = lane >> 4;
    const int m0 = blockIdx.x * 128 + wave * 32;

    f32x4 acc0[8], acc1[8];
#pragma unroll
    for (int nt = 0; nt < 8; nt++) {
        acc0[nt] = (f32x4){0.f, 0.f, 0.f, 0.f};
        acc1[nt] = (f32x4){0.f, 0.f, 0.f, 0.f};
    }

    int r0 = m0 + ar;      if (r0 > N_NODES - 1) r0 = N_NODES - 1;
    int r1 = m0 + 16 + ar; if (r1 > N_NODES - 1) r1 = N_NODES - 1;

    // ---- stage B1 ----
    {
        constexpr int CPR = K1 / 8;
#pragma unroll
        for (int ci = 0; ci < 128 * CPR / 256; ci++) {
            int c = ci * 256 + tid;
            int n = c / CPR, slot = c - n * CPR;
            uint4 v = *reinterpret_cast<const uint4*>(B1 + n * K1 + slot * 8);
            *reinterpret_cast<uint4*>(&ldsb[n * P1 + slot * 16]) = v;
        }
    }
    __syncthreads();
    // ---- K-loop 1 ----
    {
        const unsigned short* a0p = A1 + (size_t)r0 * K1 + kh * 8;
        const unsigned short* a1p = A1 + (size_t)r1 * K1 + kh * 8;
#pragma unroll
        for (int ks = 0; ks < K1 / 32; ks++) {
            bf16x8 a0 = *reinterpret_cast<const bf16x8*>(a0p + ks * 32);
            bf16x8 a1 = *reinterpret_cast<const bf16x8*>(a1p + ks * 32);
#pragma unroll
            for (int nt = 0; nt < 8; nt++) {
                bf16x8 b = *reinterpret_cast<const bf16x8*>(
                    &ldsb[(nt * 16 + ar) * P1 + ks * 64 + kh * 16]);
                acc0[nt] = __builtin_amdgcn_mfma_f32_16x16x32_bf16(b, a0, acc0[nt], 0, 0, 0);
                acc1[nt] = __builtin_amdgcn_mfma_f32_16x16x32_bf16(b, a1, acc1[nt], 0, 0, 0);
            }
        }
    }
    __syncthreads();
    // ---- stage B2 ----
    {
        constexpr int CPR = K2 / 8;
#pragma unroll
        for (int ci = 0; ci < 128 * CPR / 256; ci++) {
            int c = ci * 256 + tid;
            int n = c / CPR, slot = c - n * CPR;
            uint4 v = *reinterpret_cast<const uint4*>(B2 + n * K2 + slot * 8);
            *reinterpret_cast<uint4*>(&ldsb[n * P2 + slot * 16]) = v;
        }
    }
    __syncthreads();
    // ---- K-loop 2 ----
    {
        const unsigned short* a0p = A2 + (size_t)r0 * K2 + kh * 8;
        const unsigned short* a1p = A2 + (size_t)r1 * K2 + kh * 8;
#pragma unroll
        for (int ks = 0; ks < K2 / 32; ks++) {
            bf16x8 a0 = *reinterpret_cast<const bf16x8*>(a0p + ks * 32);
            bf16x8 a1 = *reinterpret_cast<const bf16x8*>(a1p + ks * 32);
#pragma unroll
            for (int nt = 0; nt < 8; nt++) {
                bf16x8 b = *reinterpret_cast<const bf16x8*>(
                    &ldsb[(nt * 16 + ar) * P2 + ks * 64 + kh * 16]);
                acc0[nt] = __builtin_amdgcn_mfma_f32_16x16x32_bf16(b, a0, acc0[nt], 0, 0, 0);
                acc1[nt] = __builtin_amdgcn_mfma_f32_16x16x32_bf16(b, a1, acc1[nt], 0, 0, 0);
            }
        }
    }

    // ---- epilogue ----
    float4 bv[8];
#pragma unroll
    for (int nt = 0; nt < 8; nt++)
        bv[nt] = *reinterpret_cast<const float4*>(bias + nt * 16 + kh * 4);

    int node0 = m0 + ar;
    int node1 = m0 + 16 + ar;
    if (node0 < N_NODES) {
#pragma unroll
        for (int nt = 0; nt < 8; nt++) {
            float v0 = acc0[nt][0] + bv[nt].x;
            float v1 = acc0[nt][1] + bv[nt].y;
            float v2 = acc0[nt][2] + bv[nt].z;
            float v3 = acc0[nt][3] + bv[nt].w;
            if (RELU) { v0 = fmaxf(v0, 0.f); v1 = fmaxf(v1, 0.f); v2 = fmaxf(v2, 0.f); v3 = fmaxf(v3, 0.f); }
            uint2 pk;
            pk.x = (unsigned)f2bf(v0) | ((unsigned)f2bf(v1) << 16);
            pk.y = (unsigned)f2bf(v2) | ((unsigned)f2bf(v3) << 16);
            *reinterpret_cast<uint2*>(hout + (size_t)node0 * HID + nt * 16 + kh * 4) = pk;
        }
    }
    if (node1 < N_NODES) {
#pragma unroll
        for (int nt = 0; nt < 8; nt++) {
            float v0 = acc1[nt][0] + bv[nt].x;
            float v1 = acc1[nt][1] + bv[nt].y;
            float v2 = acc1[nt][2] + bv[nt].z;
            float v3 = acc1[nt][3] + bv[nt].w;
            if (RELU) { v0 = fmaxf(v0, 0.f); v1 = fmaxf(v1, 0.f); v2 = fmaxf(v2, 0.f); v3 = fmaxf(v3, 0.f); }
            uint2 pk;
            pk.x = (unsigned)f2bf(v0) | ((unsigned)f2bf(v1) << 16);
            pk.y = (unsigned)f2bf(v2) | ((unsigned)f2bf(v3) << 16);
            *reinterpret_cast<uint2*>(hout + (size_t)node1 * HID + nt * 16 + kh * 4) = pk;
        }
    }
}

// ---------------- fused mean-pool + final linear (atomic-free) ----------------
__global__ __launch_bounds__(256) void pool_final(const unsigned short* __restrict__ h3,
                                                  const int* __restrict__ gstart,
                                                  const float* __restrict__ W_lin,
                                                  const float* __restrict__ b_lin,
                                                  float* __restrict__ out) {
    __shared__ float pp[4][HID];
    int g = blockIdx.x, t = threadIdx.x;
    int wave = t >> 6, lane = t & 63;
    int s0 = gstart[g], s1 = gstart[g + 1];
    const unsigned* h3u = reinterpret_cast<const unsigned*>(h3);
    float a0 = 0.f, a1 = 0.f;
    for (int n = s0 + wave; n < s1; n += 4) {
        unsigned v = h3u[(size_t)n * 64 + lane];
        a0 += bf2f((unsigned short)(v & 0xFFFF));
        a1 += bf2f((unsigned short)(v >> 16));
    }
    pp[wave][2 * lane] = a0;
    pp[wave][2 * lane + 1] = a1;
    __syncthreads();
    if (wave == 0) {
        float c = fmaxf((float)(s1 - s0), 1.f);
        float r0 = ((pp[0][2 * lane] + pp[1][2 * lane]) + (pp[2][2 * lane] + pp[3][2 * lane])) / c;
        float r1 = ((pp[0][2 * lane + 1] + pp[1][2 * lane + 1]) + (pp[2][2 * lane + 1] + pp[3][2 * lane + 1])) / c;
        pp[0][2 * lane] = r0;
        pp[0][2 * lane + 1] = r1;
    }
    __syncthreads();
    if (t < 4) {
        float s = b_lin[t];
#pragma unroll 8
        for (int k = 0; k < HID; k++) s += pp[0][k] * W_lin[t * HID + k];
        out[g * 4 + t] = s;
    }
}

extern "C" void kernel_launch(void* const* d_in, const int* in_sizes, int n_in,
                              void* d_out, int out_size, void* d_ws, size_t ws_size,
                              hipStream_t stream) {
    (void)in_sizes; (void)n_in; (void)out_size; (void)ws_size;
    const float* x      = (const float*)d_in[0];
    const int*   ei     = (const int*)d_in[1];
    const int*   batch  = (const int*)d_in[2];
    const float* W_rel1 = (const float*)d_in[3];
    const float* b_rel1 = (const float*)d_in[4];
    const float* W_root1= (const float*)d_in[5];
    const float* W_rel2 = (const float*)d_in[6];
    const float* b_rel2 = (const float*)d_in[7];
    const float* W_root2= (const float*)d_in[8];
    const float* W_rel3 = (const float*)d_in[9];
    const float* b_rel3 = (const float*)d_in[10];
    const float* W_root3= (const float*)d_in[11];
    const float* W_lin  = (const float*)d_in[12];
    const float* b_lin  = (const float*)d_in[13];
    const int* src = ei;
    const int* dst = ei + N_EDGES;

    char* ws = (char*)d_ws;
    size_t off = 0;
    auto alloc = [&](size_t bytes) { void* p = ws + off; off += (bytes + 255) & ~(size_t)255; return p; };
    unsigned short* aggbf    = (unsigned short*)alloc((size_t)N_NODES * HID * 2); // layer1 [.][64] slice; layer3 h3 in-place
    unsigned short* h1       = (unsigned short*)alloc((size_t)N_NODES * HID * 2); // layer 2 in-place
    unsigned short* xbf      = (unsigned short*)alloc((size_t)N_NODES * 64 * 2);
    int*            rowptr   = (int*)alloc((size_t)(N_NODES + 1) * 4);
    int*            csr_src  = (int*)alloc((size_t)N_EDGES * 4);
    unsigned*       pairs    = (unsigned*)alloc((size_t)NPART * BCAP * 4);        // 7.2 MB
    int*            bucket_cnt = (int*)alloc(NPART * 4);
    int*            gstart   = (int*)alloc((size_t)(N_GRAPHS + 1) * 4);
    unsigned short* Wb_rel1  = (unsigned short*)alloc(128 * 64 * 2);
    unsigned short* Wb_root1 = (unsigned short*)alloc(128 * 64 * 2);
    unsigned short* Wb_rel2  = (unsigned short*)alloc(128 * 128 * 2);
    unsigned short* Wb_root2 = (unsigned short*)alloc(128 * 128 * 2);
    unsigned short* Wb_rel3  = (unsigned short*)alloc(128 * 128 * 2);
    unsigned short* Wb_root3 = (unsigned short*)alloc(128 * 128 * 2);

    // ---- fused prep
    prep_all<<<(PREP_TOTAL + 255) / 256, 256, 0, stream>>>(
        x, xbf, bucket_cnt, rowptr, W_rel1, W_root1, W_rel2, W_root2, W_rel3, W_root3,
        Wb_rel1, Wb_root1, Wb_rel2, Wb_root2, Wb_rel3, Wb_root3, batch, gstart);

    // ---- CSR build: bucket by partition, then LDS-cursor local CSR (no global atomics)
    bucket_scatter<<<B1_BLOCKS, 256, 0, stream>>>(src, dst, bucket_cnt, pairs);
    local_csr<<<NPART, LCSR_T, 0, stream>>>(bucket_cnt, pairs, rowptr, csr_src);

    const int MFMA_BLOCKS = (N_NODES + 127) / 128;   // BM=128

    // ---- layer 1: pull-aggregate xbf (bf16, 128B rows), MFMA + relu -> h1
    gather_x64<<<(N_NODES * 16 + 255) / 256, 256, 0, stream>>>(xbf, rowptr, csr_src, aggbf);
    mfma_linear<64, 64, true><<<MFMA_BLOCKS, 256, 0, stream>>>(
        aggbf, xbf, Wb_rel1, Wb_root1, b_rel1, h1);

    // ---- layer 2: pull-aggregate h1, MFMA + relu -> h1 (in-place)
    gather_bf128<<<(N_NODES * 32 + 255) / 256, 256, 0, stream>>>(h1, rowptr, csr_src, aggbf);
    mfma_linear<128, 128, true><<<MFMA_BLOCKS, 256, 0, stream>>>(
        aggbf, h1, Wb_rel2, Wb_root2, b_rel2, h1);

    // ---- layer 3: pull-aggregate h1, MFMA (no relu) -> h3 (in-place over aggbf)
    gather_bf128<<<(N_NODES * 32 + 255) / 256, 256, 0, stream>>>(h1, rowptr, csr_src, aggbf);
    mfma_linear<128, 128, false><<<MFMA_BLOCKS, 256, 0, stream>>>(
        aggbf, h1, Wb_rel3, Wb_root3, b_rel3, aggbf);

    // ---- atomic-free mean-pool + final linear
    pool_final<<<N_GRAPHS, 256, 0, stream>>>(aggbf, gstart, W_lin, b_lin, (float*)d_out);
}